// Round 1
// baseline (3929.460 us; speedup 1.0000x reference)
//
#include <hip/hip_runtime.h>
#include <stdint.h>

#define L 18
#define DIM (1 << L)
#define NBLK (DIM / 256)
#define MKRY 64

// ---------------- threefry2x32 (JAX) ----------------
__device__ __forceinline__ uint32_t rotl32(uint32_t v, int r){ return (v<<r)|(v>>(32-r)); }

__device__ __forceinline__ void threefry2x32(uint32_t k0, uint32_t k1, uint32_t x0, uint32_t x1,
                                             uint32_t& o0, uint32_t& o1) {
  uint32_t k2 = k0 ^ k1 ^ 0x1BD11BDAu;
  x0 += k0; x1 += k1;
  x0+=x1; x1=rotl32(x1,13); x1^=x0;
  x0+=x1; x1=rotl32(x1,15); x1^=x0;
  x0+=x1; x1=rotl32(x1,26); x1^=x0;
  x0+=x1; x1=rotl32(x1,6);  x1^=x0;
  x0+=k1; x1+=k2+1u;
  x0+=x1; x1=rotl32(x1,17); x1^=x0;
  x0+=x1; x1=rotl32(x1,29); x1^=x0;
  x0+=x1; x1=rotl32(x1,16); x1^=x0;
  x0+=x1; x1=rotl32(x1,24); x1^=x0;
  x0+=k2; x1+=k0+2u;
  x0+=x1; x1=rotl32(x1,13); x1^=x0;
  x0+=x1; x1=rotl32(x1,15); x1^=x0;
  x0+=x1; x1=rotl32(x1,26); x1^=x0;
  x0+=x1; x1=rotl32(x1,6);  x1^=x0;
  x0+=k0; x1+=k1+3u;
  x0+=x1; x1=rotl32(x1,17); x1^=x0;
  x0+=x1; x1=rotl32(x1,29); x1^=x0;
  x0+=x1; x1=rotl32(x1,16); x1^=x0;
  x0+=x1; x1=rotl32(x1,24); x1^=x0;
  x0+=k1; x1+=k2+4u;
  x0+=x1; x1=rotl32(x1,13); x1^=x0;
  x0+=x1; x1=rotl32(x1,15); x1^=x0;
  x0+=x1; x1=rotl32(x1,26); x1^=x0;
  x0+=x1; x1=rotl32(x1,6);  x1^=x0;
  x0+=k2; x1+=k0+5u;
  o0=x0; o1=x1;
}

// XLA/chlo erf_inv f32 polynomial (Giles), contract-off to avoid FMA contraction
__device__ float jax_erfinv(float x){
  #pragma clang fp contract(off)
  float w = -log1pf(-x*x);
  float p;
  if (w < 5.0f) {
    w = w - 2.5f;
    p = 2.81022636e-08f;
    p = 3.43273939e-07f + p*w;
    p = -3.5233877e-06f + p*w;
    p = -4.39150654e-06f + p*w;
    p = 0.00021858087f + p*w;
    p = -0.00125372503f + p*w;
    p = -0.00417768164f + p*w;
    p = 0.246640727f + p*w;
    p = 1.50140941f + p*w;
  } else {
    w = sqrtf(w) - 3.0f;
    p = -0.000200214257f;
    p = 0.000100950558f + p*w;
    p = 0.00134934322f + p*w;
    p = -0.00367342844f + p*w;
    p = 0.00573950773f + p*w;
    p = -0.0076224613f + p*w;
    p = 0.00943887047f + p*w;
    p = 1.00167406f + p*w;
    p = 2.83297682f + p*w;
  }
  return p*x;
}

__device__ __forceinline__ double blockReduceSum(double x){
  __shared__ double sm[256];
  int t = threadIdx.x;
  sm[t] = x; __syncthreads();
  for (int s=128; s>0; s>>=1){ if (t<s) sm[t]+=sm[t+s]; __syncthreads(); }
  return sm[0];
}

// scal layout (floats): [0..63] alphas | [64..127] betas | [128] norm |
// [130..147] hx | [148..165] hz | [192..447] U4 (64x4)

__global__ void k_coef(const float* __restrict__ B0, const float* __restrict__ Bext,
                       const float* __restrict__ phi, float* __restrict__ scal){
  #pragma clang fp contract(off)
  int i = threadIdx.x;
  if (i < L) {
    float b0 = B0[0], be = Bext[0];
    double ph = (double)phi[i];
    float sx = (float)sin(ph), cx = (float)cos(ph);
    float Bx = b0*sx;
    float Bz = b0*cx;
    Bz = Bz + be;
    scal[130+i] = 0.5f*Bx;
    scal[148+i] = 0.5f*Bz;
  }
}

__global__ void __launch_bounds__(256) k_rng(float* __restrict__ r, double* __restrict__ part){
  #pragma clang fp contract(off)
  int i = blockIdx.x*256 + threadIdx.x;
  uint32_t o0,o1;
  threefry2x32(0u, 42u, 0u, (uint32_t)i, o0, o1);   // partitionable: counter=(0, i)
  uint32_t bits = o0 ^ o1;                           // 32-bit fold
  float f = __uint_as_float((bits >> 9) | 0x3f800000u) - 1.0f;
  const float lo = -0.99999994f;                     // nextafter(-1,0) in f32
  float u = f*2.0f;                                  // (hi-lo) rounds to 2.0f
  u = u + lo;
  u = fmaxf(lo, u);
  float n = 1.41421354f * jax_erfinv(u);             // float32(sqrt(2)) * erfinv
  r[i] = n;
  double s = (double)n*(double)n;
  double tot = blockReduceSum(s);
  if (threadIdx.x==0) part[blockIdx.x]=tot;
}

__global__ void k_reduce(const double* __restrict__ part, float* __restrict__ dst, int op){
  int t = threadIdx.x;
  double x = part[t] + part[t+256] + part[t+512] + part[t+768];
  __shared__ double sm[256];
  sm[t]=x; __syncthreads();
  for (int s=128;s>0;s>>=1){ if (t<s) sm[t]+=sm[t+s]; __syncthreads(); }
  if (t==0){
    float v = (float)sm[0];
    dst[0] = op ? sqrtf(v) : v;
  }
}

__global__ void k_scalev0(float* __restrict__ v, const float* __restrict__ nrm, float* __restrict__ v0s){
  int i = blockIdx.x*256+threadIdx.x;
  float n = nrm[0];
  float x = __fdiv_rn(v[i], n);
  v[i]=x; v0s[i]=x;
}

__global__ void __launch_bounds__(256) k_matvec(const float* __restrict__ v, float* __restrict__ w,
                        const float* __restrict__ scal, double* __restrict__ part){
  #pragma clang fp contract(off)
  int s = blockIdx.x*256 + threadIdx.x;
  float vs = v[s];
  float acc = 0.0f;
  // bonds i=0..16, site i = bit (17-i), site i+1 = bit (16-i)
  #pragma unroll
  for (int i=0;i<L-1;++i){
    int q = L-2-i;
    unsigned b2 = ((unsigned)s >> q) & 3u;
    if (b2==0u || b2==3u) { acc = acc + 0.25f*vs; }
    else if (b2==1u) { float t = -0.25f*vs; t = t + 0.5f*v[s ^ (3u<<q)]; acc = acc + t; }
    else             { float t = 0.5f*v[s ^ (3u<<q)]; t = t + (-0.25f)*vs; acc = acc + t; }
  }
  // fields i=0..17, site i = bit (17-i)
  #pragma unroll
  for (int i=0;i<L;++i){
    int p = L-1-i;
    unsigned mask = 1u<<p;
    float hx = scal[130+i], hz = scal[148+i];
    float t;
    if (s & mask) { t = hx*v[s^mask]; t = t + (-hz)*vs; }
    else          { t = hz*vs;        t = t + hx*v[s^mask]; }
    acc = acc + t;
  }
  w[s] = acc;
  double d = (double)vs * (double)acc;
  double tot = blockReduceSum(d);
  if (threadIdx.x==0) part[blockIdx.x] = tot;
}

__global__ void k_update(float* __restrict__ w, const float* __restrict__ v,
                         const float* __restrict__ vp, const float* __restrict__ scal,
                         int m, double* __restrict__ part){
  #pragma clang fp contract(off)
  int i = blockIdx.x*256+threadIdx.x;
  float alpha = scal[m];
  float bp = (m==0)? 0.0f : scal[64+m-1];
  float x = w[i];
  x = x - alpha*v[i];
  x = x - bp*vp[i];
  w[i] = x;
  double d = (double)x*(double)x;
  double tot = blockReduceSum(d);
  if (threadIdx.x==0) part[blockIdx.x]=tot;
}

__global__ void k_scale(float* __restrict__ w, const float* __restrict__ sb){
  int i = blockIdx.x*256+threadIdx.x;
  float b = fmaxf(sb[0], 1e-12f);
  w[i] = __fdiv_rn(w[i], b);
}

__global__ void k_zero(float* __restrict__ out, int n){
  int i = blockIdx.x*256+threadIdx.x;
  if (i<n) out[i]=0.0f;
}

__global__ void k_copy(float* __restrict__ dst, const float* __restrict__ src){
  int i = blockIdx.x*256+threadIdx.x;
  dst[i]=src[i];
}

__global__ void k_update2(float* __restrict__ w, const float* __restrict__ v,
                          const float* __restrict__ vp, const float* __restrict__ scal,
                          const float* __restrict__ U4, int m, float* __restrict__ out){
  #pragma clang fp contract(off)
  int i = blockIdx.x*256+threadIdx.x;
  float alpha = scal[m];
  float bp = (m==0)? 0.0f : scal[64+m-1];
  float beta = fmaxf(scal[64+m], 1e-12f);
  float vi = v[i];
  float x = w[i];
  x = x - alpha*vi;
  x = x - bp*vp[i];
  w[i] = __fdiv_rn(x, beta);
  float4 o = *(float4*)(out + 4 + 4*(size_t)i);
  o.x = o.x + vi*U4[4*m+0];
  o.y = o.y + vi*U4[4*m+1];
  o.z = o.z + vi*U4[4*m+2];
  o.w = o.w + vi*U4[4*m+3];
  *(float4*)(out + 4 + 4*(size_t)i) = o;
}

// tql2 (EISPACK) in f64, 64 threads: thread0 drives scalar recurrence,
// all threads apply rotations to their row of Z.
__global__ void k_eigh(float* __restrict__ scal, float* __restrict__ out){
  __shared__ double dd[64], ee[64], ss[64], cc[64];
  __shared__ double Z[64][65];
  __shared__ int m_sh, len_sh, jmin_sh;
  int t = threadIdx.x;
  dd[t] = (double)scal[t];
  ee[t] = (t<63)? (double)scal[64+t] : 0.0;
  for (int j=0;j<64;++j) Z[t][j] = (t==j)?1.0:0.0;
  __syncthreads();
  for (int l=0;l<64;++l){
    for (int iter=0; iter<80; ++iter){
      if (t==0){
        int m=l;
        while (m<63){
          double s2 = fabs(dd[m])+fabs(dd[m+1]);
          if (fabs(ee[m]) <= 2.220446049250313e-16 * s2) break;
          ++m;
        }
        m_sh = m;
      }
      __syncthreads();
      int m = m_sh;
      if (m==l) break;
      if (t==0){
        double g = (dd[l+1]-dd[l])/(2.0*ee[l]);
        double r = hypot(g, 1.0);
        g = dd[m]-dd[l] + ee[l]/(g + copysign(r,g));
        double s=1.0, c=1.0, p=0.0;
        int i = m-1;
        int stop = l;
        for (; i>=l; --i){
          double f = s*ee[i], b = c*ee[i];
          r = hypot(f,g);
          ee[i+1] = r;
          if (r==0.0){
            dd[i+1] -= p; ee[m]=0.0;
            stop = i+1;
            break;
          }
          s = f/r; c = g/r;
          g = dd[i+1]-p;
          double r2 = (dd[i]-g)*s + 2.0*c*b;
          p = s*r2;
          dd[i+1] = g+p;
          g = c*r2 - b;
          ss[i]=s; cc[i]=c;
        }
        if (i < l){
          dd[l] -= p; ee[l] = g; ee[m] = 0.0;
          stop = l;
        }
        len_sh = stop;
      }
      __syncthreads();
      int stop = len_sh;
      for (int i=m_sh-1; i>=stop; --i){
        double f = Z[t][i+1];
        Z[t][i+1] = ss[i]*Z[t][i] + cc[i]*f;
        Z[t][i]   = cc[i]*Z[t][i] - ss[i]*f;
      }
      __syncthreads();
    }
  }
  // ascending selection sort, permute columns
  for (int k=0;k<63;++k){
    if (t==0){
      int jm=k;
      for (int j=k+1;j<64;++j) if (dd[j]<dd[jm]) jm=j;
      jmin_sh=jm;
    }
    __syncthreads();
    int jm=jmin_sh;
    if (jm!=k){
      if (t==0){ double tmp=dd[k]; dd[k]=dd[jm]; dd[jm]=tmp; }
      double tz=Z[t][k]; Z[t][k]=Z[t][jm]; Z[t][jm]=tz;
    }
    __syncthreads();
  }
  if (t<4) out[t] = (float)dd[t];
  for (int k=0;k<4;++k) scal[192 + t*4 + k] = (float)Z[t][k];
}

extern "C" void kernel_launch(void* const* d_in, const int* in_sizes, int n_in,
                              void* d_out, int out_size, void* d_ws, size_t ws_size,
                              hipStream_t stream){
  (void)in_sizes; (void)n_in; (void)ws_size;
  const float* B0   = (const float*)d_in[0];
  const float* Bext = (const float*)d_in[1];
  const float* phi  = (const float*)d_in[2];
  float* out = (float*)d_out;

  float* vec0 = (float*)d_ws;
  float* vec1 = vec0 + DIM;
  float* vec2 = vec1 + DIM;
  float* v0s  = vec2 + DIM;
  double* part = (double*)(v0s + DIM);
  float* scal = (float*)(part + 1024);
  float* U4   = scal + 192;

  dim3 blk(256), grd(NBLK);

  hipLaunchKernelGGL(k_coef, dim3(1), dim3(32), 0, stream, B0, Bext, phi, scal);
  hipLaunchKernelGGL(k_rng, grd, blk, 0, stream, vec0, part);
  hipLaunchKernelGGL(k_reduce, dim3(1), blk, 0, stream, part, scal+128, 1);
  hipLaunchKernelGGL(k_scalev0, grd, blk, 0, stream, vec0, scal+128, v0s);

  // pass 1: alphas/betas
  float *v=vec0, *w=vec1, *pv=vec2;
  for (int m=0;m<MKRY;++m){
    hipLaunchKernelGGL(k_matvec, grd, blk, 0, stream, v, w, scal, part);
    hipLaunchKernelGGL(k_reduce, dim3(1), blk, 0, stream, part, scal+m, 0);
    hipLaunchKernelGGL(k_update, grd, blk, 0, stream, w, v, (m==0? v : pv), scal, m, part);
    hipLaunchKernelGGL(k_reduce, dim3(1), blk, 0, stream, part, scal+64+m, 1);
    hipLaunchKernelGGL(k_scale, grd, blk, 0, stream, w, scal+64+m);
    float* tmp=pv; pv=v; v=w; w=tmp;
  }

  hipLaunchKernelGGL(k_zero, dim3((out_size+255)/256), blk, 0, stream, out, out_size);
  hipLaunchKernelGGL(k_eigh, dim3(1), dim3(64), 0, stream, scal, out);

  // pass 2: rebuild V, accumulate eigvecs
  hipLaunchKernelGGL(k_copy, grd, blk, 0, stream, vec0, v0s);
  v=vec0; w=vec1; pv=vec2;
  for (int m=0;m<MKRY;++m){
    hipLaunchKernelGGL(k_matvec, grd, blk, 0, stream, v, w, scal, part);
    hipLaunchKernelGGL(k_update2, grd, blk, 0, stream, w, v, (m==0? v : pv), scal, U4, m, out);
    float* tmp=pv; pv=v; v=w; w=tmp;
  }
}